// Round 9
// baseline (2504.002 us; speedup 1.0000x reference)
//
#include <hip/hip_runtime.h>

#define NE 4096
#define BLK 512
#define NWAVE (BLK / 64)

// |d|^2.4 = exp2(1.2*log2(d*d)); v_log_f32/v_exp_f32 are base-2.
__device__ __forceinline__ float pow24(float d) {
    float d2 = d * d;
    return __builtin_amdgcn_exp2f(1.2f * __builtin_amdgcn_logf(d2));
}

__global__ __launch_bounds__(BLK) void quant_kernel(const float* __restrict__ x,
                                                    float* __restrict__ out,
                                                    const int* __restrict__ nump) {
    const int c = blockIdx.x;
    const int tid = threadIdx.x;
    const int lane = tid & 63;
    const int wv = tid >> 6;
    const int num = *nump;

    __shared__ float sx[NE];
    __shared__ float fsc[NWAVE], ffi[NWAVE], fmn[NWAVE], fmx[NWAVE];

    const float* xrow = x + (size_t)c * NE;
    for (int idx = tid; idx < NE; idx += BLK) sx[idx] = xrow[idx];
    __syncthreads();

    // ---- bitonic ascending sort of the channel in LDS (once) ----
    for (int k = 2; k <= NE; k <<= 1) {
        for (int j = k >> 1; j > 0; j >>= 1) {
            for (int base = tid; base < NE; base += BLK) {
                int ixj = base ^ j;
                if (ixj > base) {
                    float a = sx[base], b = sx[ixj];
                    if (((base & k) == 0) ? (a > b) : (a < b)) { sx[base] = b; sx[ixj] = a; }
                }
            }
            __syncthreads();
        }
    }
    // sx sorted ascending, read-only from here.

    const float xmn = fminf(sx[0], 0.0f);
    const float xmx = fmaxf(sx[NE - 1], 0.0f);
    const float xrange = xmx - xmn;
    const float rdn = xrange / (float)num;  // matches ref: xrange/num then *i

    // z held by this lane after the value-halving butterfly: bitrev4(lane&15)
    const int zmy = ((lane & 1) << 3) | ((lane & 2) << 1) | ((lane & 4) >> 1) | ((lane & 8) >> 3);
    const float zmyf = (float)zmy;

    float best_score = 1e10f;
    float best_fi = 1e9f;
    float best_min = xmn, best_max = xmx;

    for (int i = wv + 1; i <= num; i += NWAVE) {
        const float fi = (float)i;
        const float tmp_max = rdn * fi;
        const float s = fmaxf(tmp_max / 15.0f, 1e-8f);  // exact div, uniform
        const float rs = 1.0f / s;                       // exact div, uniform

        float smU[16];  // fl(s*j), statically indexed -> stays in registers
#pragma unroll
        for (int j = 0; j < 16; ++j) smU[j] = s * (float)j;

        float tacc = 0.0f;   // interior residual sum (z-independent part)
        float corr[16];      // per-z clamped corrections
#pragma unroll
        for (int z = 0; z < 16; ++z) corr[z] = 0.0f;

        for (int cc = 0; cc < 64; ++cc) {
            const float xe = sx[(cc << 6) + lane];
            const float r = rintf(xe * rs);          // integer-valued float
            const float sr = s * r;                  // fl(s*r), two-step like ref
            const float p_in = pow24(xe - sr);
            tacc += p_in;

            // wave-uniform trip counts from slice extremes (sorted slice)
            int rmaxi = (int)__int_as_float(__builtin_amdgcn_readlane(__float_as_int(r), 63));
            int rmini = (int)__int_as_float(__builtin_amdgcn_readlane(__float_as_int(r), 0));
            int nhi = rmaxi < 0 ? 0 : (rmaxi > 16 ? 16 : rmaxi);
            int nlo = rmini > 0 ? 0 : (-rmini > 16 ? 16 : -rmini);
            nhi = __builtin_amdgcn_readfirstlane(nhi);
            nlo = __builtin_amdgcn_readfirstlane(nlo);

            // Duff switch: executes exactly nhi bodies (j = nhi-1 .. 0), scalar jump.
            // Active lanes (r > j): arg = xe - fl(s*j) exactly; inactive: term == 0.
#define UPT(J) corr[15 - (J)] += pow24(xe - fminf(sr, smU[(J)])) - p_in;
            switch (nhi) {
                case 16: UPT(15) [[fallthrough]];
                case 15: UPT(14) [[fallthrough]];
                case 14: UPT(13) [[fallthrough]];
                case 13: UPT(12) [[fallthrough]];
                case 12: UPT(11) [[fallthrough]];
                case 11: UPT(10) [[fallthrough]];
                case 10: UPT(9)  [[fallthrough]];
                case 9:  UPT(8)  [[fallthrough]];
                case 8:  UPT(7)  [[fallthrough]];
                case 7:  UPT(6)  [[fallthrough]];
                case 6:  UPT(5)  [[fallthrough]];
                case 5:  UPT(4)  [[fallthrough]];
                case 4:  UPT(3)  [[fallthrough]];
                case 3:  UPT(2)  [[fallthrough]];
                case 2:  UPT(1)  [[fallthrough]];
                case 1:  UPT(0)  break;
                default: break;
            }
#undef UPT
#define DNT(J) corr[(J)] += pow24(xe - fmaxf(sr, -smU[(J)])) - p_in;
            switch (nlo) {
                case 16: DNT(15) [[fallthrough]];
                case 15: DNT(14) [[fallthrough]];
                case 14: DNT(13) [[fallthrough]];
                case 13: DNT(12) [[fallthrough]];
                case 12: DNT(11) [[fallthrough]];
                case 11: DNT(10) [[fallthrough]];
                case 10: DNT(9)  [[fallthrough]];
                case 9:  DNT(8)  [[fallthrough]];
                case 8:  DNT(7)  [[fallthrough]];
                case 7:  DNT(6)  [[fallthrough]];
                case 6:  DNT(5)  [[fallthrough]];
                case 5:  DNT(4)  [[fallthrough]];
                case 4:  DNT(3)  [[fallthrough]];
                case 3:  DNT(2)  [[fallthrough]];
                case 2:  DNT(1)  [[fallthrough]];
                case 1:  DNT(0)  break;
                default: break;
            }
#undef DNT
        }

        // ---- full-wave butterfly on tacc (identical value on all lanes) ----
#pragma unroll
        for (int k = 1; k < 64; k <<= 1) tacc += __shfl_xor(tacc, k, 64);

        // ---- in-register value-halving butterfly: 16 corrs over 64 lanes ----
#pragma unroll
        for (int q = 0; q < 8; ++q) {
            float send = (lane & 1) ? corr[q] : corr[q + 8];
            float keep = (lane & 1) ? corr[q + 8] : corr[q];
            corr[q] = keep + __shfl_xor(send, 1, 64);
        }
#pragma unroll
        for (int q = 0; q < 4; ++q) {
            float send = (lane & 2) ? corr[q] : corr[q + 4];
            float keep = (lane & 2) ? corr[q + 4] : corr[q];
            corr[q] = keep + __shfl_xor(send, 2, 64);
        }
#pragma unroll
        for (int q = 0; q < 2; ++q) {
            float send = (lane & 4) ? corr[q] : corr[q + 2];
            float keep = (lane & 4) ? corr[q + 2] : corr[q];
            corr[q] = keep + __shfl_xor(send, 4, 64);
        }
        {
            float send = (lane & 8) ? corr[0] : corr[1];
            float keep = (lane & 8) ? corr[1] : corr[0];
            corr[0] = keep + __shfl_xor(send, 8, 64);
        }
        corr[0] += __shfl_xor(corr[0], 16, 64);
        corr[0] += __shfl_xor(corr[0], 32, 64);
        float sc = (tacc + corr[0]) * (1.0f / 4096.0f);  // mean = sum * 2^-12

        // lex argmin over z (tie -> smaller z), result uniform across wave
        float bsz = sc, bzz = zmyf;
#pragma unroll
        for (int k = 1; k < 64; k <<= 1) {
            float os = __shfl_xor(bsz, k, 64);
            float oz = __shfl_xor(bzz, k, 64);
            bool take = (os < bsz) || ((os == bsz) && (oz < bzz));
            bsz = take ? os : bsz;
            bzz = take ? oz : bzz;
        }
        if (bsz < best_score) {                          // strict <, ascending i per wave
            best_score = bsz;
            best_fi = fi;
            float zs = bzz * s;
            best_min = -zs;                              // new_min = -zbest*delta
            best_max = tmp_max - zs;                     // new_max = tmp_max - zbest*delta
        }
    }

    // ---- cross-wave lex-min on (score, i): matches sequential strict-< semantics ----
    if (lane == 0) { fsc[wv] = best_score; ffi[wv] = best_fi; fmn[wv] = best_min; fmx[wv] = best_max; }
    __syncthreads();
    float bs = fsc[0], bi = ffi[0], bm = fmn[0], bxv = fmx[0];
#pragma unroll
    for (int w = 1; w < NWAVE; ++w) {
        bool take = (fsc[w] < bs) || ((fsc[w] == bs) && (ffi[w] < bi));
        if (take) { bs = fsc[w]; bi = ffi[w]; bm = fmn[w]; bxv = fmx[w]; }
    }

    const float min_neg = fminf(bm, 0.0f);
    const float max_pos = fmaxf(bxv, 0.0f);
    const float scale = fmaxf((max_pos - min_neg) / 15.0f, 1e-8f);
    const float zero = fminf(fmaxf(0.0f - rintf(min_neg / scale), 0.0f), 15.0f);

    float* orow = out + (size_t)c * NE;
    for (int idx = tid; idx < NE; idx += BLK) {
        float xe = xrow[idx];                            // original order, exact div
        float q = fminf(fmaxf(rintf(xe / scale) + zero, 0.0f), 15.0f);
        orow[idx] = scale * (q - zero);
    }
}

extern "C" void kernel_launch(void* const* d_in, const int* in_sizes, int n_in,
                              void* d_out, int out_size, void* d_ws, size_t ws_size,
                              hipStream_t stream) {
    const float* x = (const float*)d_in[0];
    const int* nump = (const int*)d_in[1];
    float* out = (float*)d_out;
    const int C = out_size / NE;
    quant_kernel<<<C, BLK, 0, stream>>>(x, out, nump);
}

// Round 10
// 1159.338 us; speedup vs baseline: 2.1599x; 2.1599x over previous
//
#include <hip/hip_runtime.h>

#define NE 4096
#define BLK 512
#define NWAVE (BLK / 64)

// |d|^2.4 = exp2(1.2*log2(d*d)); v_log_f32/v_exp_f32 are base-2.
__device__ __forceinline__ float pow24(float d) {
    float d2 = d * d;
    return __builtin_amdgcn_exp2f(1.2f * __builtin_amdgcn_logf(d2));
}

__global__ __launch_bounds__(BLK) void quant_kernel(const float* __restrict__ x,
                                                    float* __restrict__ out,
                                                    const int* __restrict__ nump) {
    const int c = blockIdx.x;
    const int tid = threadIdx.x;
    const int lane = tid & 63;
    const int wv = tid >> 6;
    const int num = *nump;

    __shared__ float sx[NE];
    __shared__ float fsc[NWAVE], ffi[NWAVE], fmn[NWAVE], fmx[NWAVE];

    const float* xrow = x + (size_t)c * NE;
    for (int idx = tid; idx < NE; idx += BLK) sx[idx] = xrow[idx];
    __syncthreads();

    // ---- bitonic ascending sort of the channel in LDS (once) ----
    for (int k = 2; k <= NE; k <<= 1) {
        for (int j = k >> 1; j > 0; j >>= 1) {
            for (int base = tid; base < NE; base += BLK) {
                int ixj = base ^ j;
                if (ixj > base) {
                    float a = sx[base], b = sx[ixj];
                    if (((base & k) == 0) ? (a > b) : (a < b)) { sx[base] = b; sx[ixj] = a; }
                }
            }
            __syncthreads();
        }
    }
    // sx sorted ascending, read-only from here.

    const float xmn = fminf(sx[0], 0.0f);
    const float xmx = fmaxf(sx[NE - 1], 0.0f);
    const float xrange = xmx - xmn;
    const float rdn = xrange / (float)num;  // matches ref: xrange/num then *i

    // z held by this lane after the value-halving butterfly: bitrev4(lane&15)
    const int zmy = ((lane & 1) << 3) | ((lane & 2) << 1) | ((lane & 4) >> 1) | ((lane & 8) >> 3);
    const float zmyf = (float)zmy;

    float best_score = 1e10f;
    float best_fi = 1e9f;
    float best_min = xmn, best_max = xmx;

    // each wave owns a strided 1/8 of the i-range; no barriers in this loop
    for (int i = wv + 1; i <= num; i += NWAVE) {
        const float fi = (float)i;
        const float tmp_max = rdn * fi;
        const float s = fmaxf(tmp_max / 15.0f, 1e-8f);  // exact div, uniform
        const float ns = -s;
        const float rs = 1.0f / s;                       // exact div, uniform

        float tacc = 0.0f;   // sum of interior residuals (z-independent part)
        float corr[16];      // per-z clamped corrections
#pragma unroll
        for (int z = 0; z < 16; ++z) corr[z] = 0.0f;

        for (int cc = 0; cc < 64; ++cc) {
            const float xe = sx[(cc << 6) + lane];       // sorted slice
            const float r = rintf(xe * rs);              // integer-valued float
            const float p_in = pow24(fmaf(ns, r, xe));
            tacc += p_in;

            // wave-uniform clamp counts from slice extremes (lane0=min, lane63=max)
            const float rmaxw = __int_as_float(__builtin_amdgcn_readlane(__float_as_int(r), 63));
            const float rminw = __int_as_float(__builtin_amdgcn_readlane(__float_as_int(r), 0));
            const int nhi = (int)fminf(fmaxf(rmaxw, 0.0f), 16.0f);
            const int nlo = (int)fminf(fmaxf(-rminw, 0.0f), 16.0f);

            // upper-clamped: z = 15-j, active iff r > j, d = xe - s*j
#pragma unroll
            for (int j = 0; j < 16; ++j) {
                if (j >= nhi) break;                     // uniform (SGPR) break
                const float jf = (float)j;
                const float ph = pow24(fmaf(ns, jf, xe));
                corr[15 - j] += (r > jf) ? (ph - p_in) : 0.0f;
            }
            // lower-clamped: z = j, active iff r < -j, d = xe + s*j
#pragma unroll
            for (int j = 0; j < 16; ++j) {
                if (j >= nlo) break;
                const float jf = (float)j;
                const float pl = pow24(fmaf(s, jf, xe));
                corr[j] += (r < -jf) ? (pl - p_in) : 0.0f;
            }
        }

        // ---- full-wave butterfly on tacc (identical value on all lanes) ----
#pragma unroll
        for (int k = 1; k < 64; k <<= 1) tacc += __shfl_xor(tacc, k, 64);

        // ---- in-register value-halving butterfly: 16 corrs over 64 lanes ----
#pragma unroll
        for (int q = 0; q < 8; ++q) {
            float send = (lane & 1) ? corr[q] : corr[q + 8];
            float keep = (lane & 1) ? corr[q + 8] : corr[q];
            corr[q] = keep + __shfl_xor(send, 1, 64);
        }
#pragma unroll
        for (int q = 0; q < 4; ++q) {
            float send = (lane & 2) ? corr[q] : corr[q + 4];
            float keep = (lane & 2) ? corr[q + 4] : corr[q];
            corr[q] = keep + __shfl_xor(send, 2, 64);
        }
#pragma unroll
        for (int q = 0; q < 2; ++q) {
            float send = (lane & 4) ? corr[q] : corr[q + 2];
            float keep = (lane & 4) ? corr[q + 2] : corr[q];
            corr[q] = keep + __shfl_xor(send, 4, 64);
        }
        {
            float send = (lane & 8) ? corr[0] : corr[1];
            float keep = (lane & 8) ? corr[1] : corr[0];
            corr[0] = keep + __shfl_xor(send, 8, 64);
        }
        corr[0] += __shfl_xor(corr[0], 16, 64);
        corr[0] += __shfl_xor(corr[0], 32, 64);
        float sc = (tacc + corr[0]) * (1.0f / 4096.0f);  // mean = sum * 2^-12

        // lex argmin over z (tie -> smaller z), result uniform across wave
        float bsz = sc, bzz = zmyf;
#pragma unroll
        for (int k = 1; k < 64; k <<= 1) {
            float os = __shfl_xor(bsz, k, 64);
            float oz = __shfl_xor(bzz, k, 64);
            bool take = (os < bsz) || ((os == bsz) && (oz < bzz));
            bsz = take ? os : bsz;
            bzz = take ? oz : bzz;
        }
        if (bsz < best_score) {                          // strict <, ascending i per wave
            best_score = bsz;
            best_fi = fi;
            float zs = bzz * s;
            best_min = -zs;                              // new_min = -zbest*delta
            best_max = tmp_max - zs;                     // new_max = tmp_max - zbest*delta
        }
    }

    // ---- cross-wave lex-min on (score, i): matches sequential strict-< semantics ----
    if (lane == 0) { fsc[wv] = best_score; ffi[wv] = best_fi; fmn[wv] = best_min; fmx[wv] = best_max; }
    __syncthreads();
    float bs = fsc[0], bi = ffi[0], bm = fmn[0], bxv = fmx[0];
#pragma unroll
    for (int w = 1; w < NWAVE; ++w) {
        bool take = (fsc[w] < bs) || ((fsc[w] == bs) && (ffi[w] < bi));
        if (take) { bs = fsc[w]; bi = ffi[w]; bm = fmn[w]; bxv = fmx[w]; }
    }

    const float min_neg = fminf(bm, 0.0f);
    const float max_pos = fmaxf(bxv, 0.0f);
    const float scale = fmaxf((max_pos - min_neg) / 15.0f, 1e-8f);
    const float zero = fminf(fmaxf(0.0f - rintf(min_neg / scale), 0.0f), 15.0f);

    float* orow = out + (size_t)c * NE;
    for (int idx = tid; idx < NE; idx += BLK) {
        float xe = xrow[idx];                            // original order, exact div
        float q = fminf(fmaxf(rintf(xe / scale) + zero, 0.0f), 15.0f);
        orow[idx] = scale * (q - zero);
    }
}

extern "C" void kernel_launch(void* const* d_in, const int* in_sizes, int n_in,
                              void* d_out, int out_size, void* d_ws, size_t ws_size,
                              hipStream_t stream) {
    const float* x = (const float*)d_in[0];
    const int* nump = (const int*)d_in[1];
    float* out = (float*)d_out;
    const int C = out_size / NE;
    quant_kernel<<<C, BLK, 0, stream>>>(x, out, nump);
}